// Round 1
// 4025.665 us; speedup vs baseline: 1.0058x; 1.0058x over previous
//
#include <hip/hip_runtime.h>
#include <math.h>

// Dims fixed by the reference: MEM = NF = MSG = 256.
#define MEMD 256
#define BM   32     // event rows per block; 100000 % 32 == 0 -> 3125 blocks
#define NT   256    // 4 waves
#define RW   8      // rows per lane (one row-quarter)

// Transposed gate weights: [WihT | WhhT], each [256 k][768 j] row-major.
__device__ float g_WT[2 * 3 * MEMD * MEMD];

__global__ void transpose_gates(const float* __restrict__ Wih,
                                const float* __restrict__ Whh)
{
    __shared__ float tile[32][33];
    const float* src = blockIdx.z ? Whh : Wih;
    float* dst = g_WT + (size_t)blockIdx.z * 3 * MEMD * MEMD;
    const int j0 = blockIdx.x * 32;   // src row   (0..767)
    const int k0 = blockIdx.y * 32;   // src col   (0..255)
    const int tx = threadIdx.x & 31, ty = threadIdx.x >> 5;
#pragma unroll
    for (int r = ty; r < 32; r += 8)
        tile[r][tx] = src[(size_t)(j0 + r) * MEMD + (k0 + tx)];
    __syncthreads();
#pragma unroll
    for (int r = ty; r < 32; r += 8)
        dst[(size_t)(k0 + r) * (3 * MEMD) + (j0 + tx)] = tile[tx][r];
}

__device__ __forceinline__ float sigmoidf_(float x) { return 1.0f / (1.0f + __expf(-x)); }

__device__ __forceinline__ void fma4(float4& a, float s, const float4& w) {
    a.x = fmaf(s, w.x, a.x);
    a.y = fmaf(s, w.y, a.y);
    a.z = fmaf(s, w.z, a.z);
    a.w = fmaf(s, w.w, a.w);
}

#define FMA16(ACC, A, W) \
    do { fma4(ACC, (A).x, (W)[0]); fma4(ACC, (A).y, (W)[1]); \
         fma4(ACC, (A).z, (W)[2]); fma4(ACC, (A).w, (W)[3]); } while (0)

__global__ __launch_bounds__(NT, 3)
void tgn_fused(const float* __restrict__ memory,
               const int*   __restrict__ node_idxs,
               const float* __restrict__ nf,
               const float* __restrict__ ef,
               const float* __restrict__ tstamps,
               const float* __restrict__ W1, const float* __restrict__ b1,
               const float* __restrict__ W2, const float* __restrict__ b2,
               const float* __restrict__ bih, const float* __restrict__ bhh,
               float* __restrict__ out_mem, float* __restrict__ out_msg,
               float* __restrict__ out_lu)
{
    __shared__ float ms[BM][MEMD];   // relu(t1), then m. 32 KB only.

    const int t  = threadIdx.x;
    const int ln = t & 63;
    const int wv = t >> 6;            // wave -> 64-column slice
    const int rq = ln >> 4;           // row-quarter 0..3
    const int cq = ln & 15;           // col chunk within slice
    const int wc = wv * 16 + cq;      // float4 column chunk 0..63
    const int c0 = wc * 4;            // first of this lane's 4 columns
    const int rbase = rq * 8;         // first of this lane's 8 rows (block-local)
    const int row0 = blockIdx.x * BM;

    int idxv[RW];
    const float* hb[RW];
#pragma unroll
    for (int i = 0; i < RW; ++i) {
        idxv[i] = node_idxs[row0 + rbase + i];
        hb[i]   = memory + (size_t)idxv[i] * MEMD;
    }
    const float* nfb = nf + (size_t)(row0 + rbase) * MEMD;
    const float* efb = ef + (size_t)(row0 + rbase) * MEMD;

    const float4* W1f4 = (const float4*)W1;

    // ---------------- layer 1: t1 = [nf | h | ef] @ W1 + b1 ----------------
    float4 acc[RW];
    {
        float4 b = ((const float4*)b1)[wc];
#pragma unroll
        for (int i = 0; i < RW; ++i) acc[i] = b;
    }
    for (int k4 = 0; k4 < 64; ++k4) {
        float4 wnf[4], whh[4], wef[4];
#pragma unroll
        for (int kk = 0; kk < 4; ++kk) {
            wnf[kk] = W1f4[(size_t)(      4 * k4 + kk) * 64 + wc];
            whh[kk] = W1f4[(size_t)(256 + 4 * k4 + kk) * 64 + wc];
            wef[kk] = W1f4[(size_t)(512 + 4 * k4 + kk) * 64 + wc];
        }
#pragma unroll
        for (int i = 0; i < RW; ++i) {
            float4 a0 = *(const float4*)(nfb + (size_t)i * MEMD + k4 * 4);
            float4 a1 = *(const float4*)(hb[i] + k4 * 4);
            float4 a2 = *(const float4*)(efb + (size_t)i * MEMD + k4 * 4);
            FMA16(acc[i], a0, wnf);
            FMA16(acc[i], a1, whh);
            FMA16(acc[i], a2, wef);
        }
    }
    // relu -> ms
#pragma unroll
    for (int i = 0; i < RW; ++i) {
        float4 v = acc[i];
        v.x = fmaxf(v.x, 0.f); v.y = fmaxf(v.y, 0.f);
        v.z = fmaxf(v.z, 0.f); v.w = fmaxf(v.w, 0.f);
        ((float4*)ms[rbase + i])[wc] = v;
    }
    __syncthreads();

    // ---------------- layer 2: m = relu(t1) @ W2 + b2 ----------------
    const float4* W2f4 = (const float4*)W2;
    float4 acc2[RW];
    {
        float4 b = ((const float4*)b2)[wc];
#pragma unroll
        for (int i = 0; i < RW; ++i) acc2[i] = b;
    }
    for (int k4 = 0; k4 < 64; ++k4) {
        float4 w[4];
#pragma unroll
        for (int kk = 0; kk < 4; ++kk) w[kk] = W2f4[(size_t)(4 * k4 + kk) * 64 + wc];
#pragma unroll
        for (int i = 0; i < RW; ++i) {
            float4 a = ((const float4*)ms[rbase + i])[k4];
            FMA16(acc2[i], a, w);
        }
    }
    __syncthreads();   // all reads of relu(t1) complete before overwrite
#pragma unroll
    for (int i = 0; i < RW; ++i) {
        *(float4*)(out_msg + (size_t)idxv[i] * MEMD + c0) = acc2[i];
        ((float4*)ms[rbase + i])[wc] = acc2[i];
    }
    __syncthreads();

    const float4* WTih = (const float4*)g_WT;                      // [k][192 f4]
    const float4* WThh = (const float4*)(g_WT + 3 * MEMD * MEMD);

    // ---------------- gate r: sigmoid(m@Wih_r^T + h@Whh_r^T + b) ----------------
    float4 gr[RW];
    {
        float4 bi = ((const float4*)bih)[wc];
        float4 bh = ((const float4*)bhh)[wc];
        float4 b = make_float4(bi.x + bh.x, bi.y + bh.y, bi.z + bh.z, bi.w + bh.w);
#pragma unroll
        for (int i = 0; i < RW; ++i) gr[i] = b;
    }
    for (int k4 = 0; k4 < 64; ++k4) {
        float4 wm[4], wh[4];
#pragma unroll
        for (int kk = 0; kk < 4; ++kk) {
            wm[kk] = WTih[(size_t)(4 * k4 + kk) * 192 + wc];
            wh[kk] = WThh[(size_t)(4 * k4 + kk) * 192 + wc];
        }
#pragma unroll
        for (int i = 0; i < RW; ++i) {
            float4 am = ((const float4*)ms[rbase + i])[k4];
            float4 ah = *(const float4*)(hb[i] + k4 * 4);
            FMA16(gr[i], am, wm);
            FMA16(gr[i], ah, wh);
        }
    }
#pragma unroll
    for (int i = 0; i < RW; ++i) {
        gr[i].x = sigmoidf_(gr[i].x); gr[i].y = sigmoidf_(gr[i].y);
        gr[i].z = sigmoidf_(gr[i].z); gr[i].w = sigmoidf_(gr[i].w);
    }

    // ---------------- gate n, h-part: gh = h@Whh_n^T + bhh_n ----------------
    float4 gh[RW];
    {
        float4 b = ((const float4*)bhh)[128 + wc];
#pragma unroll
        for (int i = 0; i < RW; ++i) gh[i] = b;
    }
    for (int k4 = 0; k4 < 64; ++k4) {
        float4 w[4];
#pragma unroll
        for (int kk = 0; kk < 4; ++kk) w[kk] = WThh[(size_t)(4 * k4 + kk) * 192 + 128 + wc];
#pragma unroll
        for (int i = 0; i < RW; ++i) {
            float4 ah = *(const float4*)(hb[i] + k4 * 4);
            FMA16(gh[i], ah, w);
        }
    }
    // ---------------- gate n, m-part + combine: n = tanh(gx + r*gh) ----------------
    float4 gn[RW];
    {
        float4 b = ((const float4*)bih)[128 + wc];
#pragma unroll
        for (int i = 0; i < RW; ++i) gn[i] = b;
    }
    for (int k4 = 0; k4 < 64; ++k4) {
        float4 w[4];
#pragma unroll
        for (int kk = 0; kk < 4; ++kk) w[kk] = WTih[(size_t)(4 * k4 + kk) * 192 + 128 + wc];
#pragma unroll
        for (int i = 0; i < RW; ++i) {
            float4 am = ((const float4*)ms[rbase + i])[k4];
            FMA16(gn[i], am, w);
        }
    }
#pragma unroll
    for (int i = 0; i < RW; ++i) {
        gn[i].x = tanhf(gn[i].x + gr[i].x * gh[i].x);
        gn[i].y = tanhf(gn[i].y + gr[i].y * gh[i].y);
        gn[i].z = tanhf(gn[i].z + gr[i].z * gh[i].z);
        gn[i].w = tanhf(gn[i].w + gr[i].w * gh[i].w);
    }

    // ---------------- gate z ----------------
    float4 gz[RW];
    {
        float4 bi = ((const float4*)bih)[64 + wc];
        float4 bh = ((const float4*)bhh)[64 + wc];
        float4 b = make_float4(bi.x + bh.x, bi.y + bh.y, bi.z + bh.z, bi.w + bh.w);
#pragma unroll
        for (int i = 0; i < RW; ++i) gz[i] = b;
    }
    for (int k4 = 0; k4 < 64; ++k4) {
        float4 wm[4], wh[4];
#pragma unroll
        for (int kk = 0; kk < 4; ++kk) {
            wm[kk] = WTih[(size_t)(4 * k4 + kk) * 192 + 64 + wc];
            wh[kk] = WThh[(size_t)(4 * k4 + kk) * 192 + 64 + wc];
        }
#pragma unroll
        for (int i = 0; i < RW; ++i) {
            float4 am = ((const float4*)ms[rbase + i])[k4];
            float4 ah = *(const float4*)(hb[i] + k4 * 4);
            FMA16(gz[i], am, wm);
            FMA16(gz[i], ah, wh);
        }
    }

    // ---------------- h_new = n + z*(h-n); scatter ----------------
#pragma unroll
    for (int i = 0; i < RW; ++i) {
        float z0 = sigmoidf_(gz[i].x), z1 = sigmoidf_(gz[i].y);
        float z2 = sigmoidf_(gz[i].z), z3 = sigmoidf_(gz[i].w);
        float4 h4 = *(const float4*)(hb[i] + c0);
        float4 o;
        o.x = fmaf(z0, h4.x - gn[i].x, gn[i].x);
        o.y = fmaf(z1, h4.y - gn[i].y, gn[i].y);
        o.z = fmaf(z2, h4.z - gn[i].z, gn[i].z);
        o.w = fmaf(z3, h4.w - gn[i].w, gn[i].w);
        *(float4*)(out_mem + (size_t)idxv[i] * MEMD + c0) = o;
    }
    if (t < BM) out_lu[node_idxs[row0 + t]] = tstamps[row0 + t];
}

extern "C" void kernel_launch(void* const* d_in, const int* in_sizes, int n_in,
                              void* d_out, int out_size, void* d_ws, size_t ws_size,
                              hipStream_t stream)
{
    const float* memory      = (const float*)d_in[0];
    const float* messages    = (const float*)d_in[1];
    const float* last_update = (const float*)d_in[2];
    const int*   node_idxs   = (const int*)  d_in[3];
    const float* nf          = (const float*)d_in[4];
    const float* ef          = (const float*)d_in[5];
    const float* tstamps     = (const float*)d_in[6];
    const float* W1          = (const float*)d_in[7];
    const float* b1          = (const float*)d_in[8];
    const float* W2          = (const float*)d_in[9];
    const float* b2          = (const float*)d_in[10];
    const float* Wih         = (const float*)d_in[11];
    const float* Whh         = (const float*)d_in[12];
    const float* bih         = (const float*)d_in[13];
    const float* bhh         = (const float*)d_in[14];

    const int n_nodes = in_sizes[2];   // 300000
    const int Bn      = in_sizes[3];   // 100000

    float* out_mem = (float*)d_out;
    float* out_msg = out_mem + (size_t)n_nodes * MEMD;
    float* out_lu  = out_msg + (size_t)n_nodes * MEMD;

    // Pass-through copies (graph-capture-safe d2d); scattered rows overwritten below.
    hipMemcpyAsync(out_mem, memory,      (size_t)n_nodes * MEMD * sizeof(float),
                   hipMemcpyDeviceToDevice, stream);
    hipMemcpyAsync(out_msg, messages,    (size_t)n_nodes * MEMD * sizeof(float),
                   hipMemcpyDeviceToDevice, stream);
    hipMemcpyAsync(out_lu,  last_update, (size_t)n_nodes * sizeof(float),
                   hipMemcpyDeviceToDevice, stream);

    // Transpose gate weights into k-major layout (device global, ~1.5 MB).
    transpose_gates<<<dim3(24, 8, 2), NT, 0, stream>>>(Wih, Whh);

    // Bn == 100000, divisible by BM=32 -> exact grid.
    dim3 grid(Bn / BM);
    tgn_fused<<<grid, NT, 0, stream>>>(memory, node_idxs, nf, ef, tstamps,
                                       W1, b1, W2, b2, bih, bhh,
                                       out_mem, out_msg, out_lu);
}